// Round 2
// baseline (30.999 us; speedup 1.0000x reference)
//
#include <hip/hip_runtime.h>

#define BATCH  128
#define NB     14
#define TS     1096          // num_time_samples
#define LTOT   24            // channel length
#define FRAME  (TS + LTOT - 1)          // 1119
#define OUTLEN ((NB - 1) * TS + FRAME)  // 15367

// ---- scalar fallback: one output sample (seams, frame edges, tails) ----
__device__ __forceinline__ float conv_one(const float* __restrict__ x,
                                          const float* __restrict__ h,
                                          int b, int o) {
    int n1 = o / TS; if (n1 > NB - 1) n1 = NB - 1;
    const int i1 = o - n1 * TS;
    float acc = 0.0f;
    {
        const float* xb = x + ((size_t)b * NB + n1) * TS;
        const float* hb = h + ((size_t)b * NB + n1) * LTOT;
        int jlo = i1 - (TS - 1); if (jlo < 0) jlo = 0;
        int jhi = i1 < LTOT - 1 ? i1 : LTOT - 1;
        for (int j = jlo; j <= jhi; ++j)
            acc = fmaf(hb[j], xb[i1 - j], acc);
    }
    if (i1 < LTOT - 1 && n1 > 0) {
        const int i0 = i1 + TS;
        const float* xb = x + ((size_t)b * NB + n1 - 1) * TS;
        const float* hb = h + ((size_t)b * NB + n1 - 1) * LTOT;
        for (int j = i0 - (TS - 1); j < LTOT; ++j)
            acc = fmaf(hb[j], xb[i0 - j], acc);
    }
    return acc;
}

// ---- fast path: 4 outputs/thread, sliding register window, all-float4 ----
// P = b & 3 compensates the per-batch output-base misalignment
// (OUTLEN*4 = 61468 B; 61468*b + 4*P + 16*t is 16B-aligned when P == b mod 4).
template<int P>
__device__ __forceinline__ void body(const float* __restrict__ x,
                                     const float* __restrict__ h,
                                     float* __restrict__ out) {
    const int t = blockIdx.x * blockDim.x + threadIdx.x;
    const int b = blockIdx.y;
    float* __restrict__ outb = out + (size_t)b * OUTLEN;

    if (P > 0 && t == 0) {              // leading P outputs not covered by tiles
        #pragma unroll
        for (int o = 0; o < P; ++o) outb[o] = conv_one(x, h, b, o);
    }

    const int o0 = P + 4 * t;
    if (o0 >= OUTLEN) return;

    int n1 = o0 / TS; if (n1 > NB - 1) n1 = NB - 1;
    const int i1 = o0 - n1 * TS;

    constexpr int NLOAD = (P == 0) ? 7 : 8;       // float4 x-loads
    constexpr int IHI = 1120 + P - 4 * NLOAD;     // max i1 keeping window in-frame

    if (i1 >= 24 + P && i1 <= IHI) {
        const float* __restrict__ xb = x + ((size_t)b * NB + n1) * TS;
        const float* __restrict__ hb = h + ((size_t)b * NB + n1) * LTOT;
        const int ws = i1 - 24 - P;               // multiple of 4 -> 16B aligned

        float xw[4 * NLOAD];
        #pragma unroll
        for (int q = 0; q < NLOAD; ++q) {
            float4 v = *(const float4*)(xb + ws + 4 * q);
            xw[4*q+0] = v.x; xw[4*q+1] = v.y; xw[4*q+2] = v.z; xw[4*q+3] = v.w;
        }
        float hw[LTOT];
        #pragma unroll
        for (int q = 0; q < LTOT / 4; ++q) {
            float4 v = *(const float4*)(hb + 4 * q);
            hw[4*q+0] = v.x; hw[4*q+1] = v.y; hw[4*q+2] = v.z; hw[4*q+3] = v.w;
        }

        float4 acc = make_float4(0.f, 0.f, 0.f, 0.f);
        #pragma unroll
        for (int j = 0; j < LTOT; ++j) {          // all indices compile-time
            acc.x = fmaf(hw[j], xw[24 + P + 0 - j], acc.x);
            acc.y = fmaf(hw[j], xw[24 + P + 1 - j], acc.y);
            acc.z = fmaf(hw[j], xw[24 + P + 2 - j], acc.z);
            acc.w = fmaf(hw[j], xw[24 + P + 3 - j], acc.w);
        }
        *(float4*)(outb + o0) = acc;              // 16B aligned by construction
    } else {
        #pragma unroll
        for (int k = 0; k < 4; ++k) {
            const int o = o0 + k;
            if (o < OUTLEN) outb[o] = conv_one(x, h, b, o);
        }
    }
}

__global__ __launch_bounds__(256)
void atc_tile4_kernel(const float* __restrict__ x,
                      const float* __restrict__ h,
                      float* __restrict__ out) {
    switch (blockIdx.y & 3) {                     // wave-uniform dispatch
        case 0: body<0>(x, h, out); break;
        case 1: body<1>(x, h, out); break;
        case 2: body<2>(x, h, out); break;
        case 3: body<3>(x, h, out); break;
    }
}

extern "C" void kernel_launch(void* const* d_in, const int* in_sizes, int n_in,
                              void* d_out, int out_size, void* d_ws, size_t ws_size,
                              hipStream_t stream) {
    const float* x = (const float*)d_in[0];   // [B, NB, TS]
    const float* h = (const float*)d_in[1];   // [B, NB, LTOT]
    float* out = (float*)d_out;               // [B, OUTLEN]

    const int tiles = (OUTLEN + 3) / 4;       // 3842 threads per batch
    dim3 block(256, 1, 1);
    dim3 grid((tiles + 255) / 256, BATCH, 1);
    atc_tile4_kernel<<<grid, block, 0, stream>>>(x, h, out);
}

// Round 3
// 25.369 us; speedup vs baseline: 1.2219x; 1.2219x over previous
//
#include <hip/hip_runtime.h>

#define BATCH  128
#define NB     14
#define TS     1096
#define LTOT   24
#define FRAME  (TS + LTOT - 1)            // 1119
#define OUTLEN ((NB - 1) * TS + FRAME)    // 15367
#define XLEN   (NB * TS)                  // 15344 (flat x per batch)

// Flat formulation: out[b,o] = sum_{j=0..23} xflat[b,o-j] * h[b,(o-j)/TS, j]
// (taps with o-j outside [0, XLEN) contribute 0). This is algebraically equal
// to the reference's per-frame conv + overlap_add because hop == TS == frame
// x-length, so frame n's sample i sits at flat position n*TS + i.
__global__ __launch_bounds__(256)
void atc_flat2_kernel(const float* __restrict__ x,
                      const float* __restrict__ h,
                      float* __restrict__ out) {
    const int t = blockIdx.x * blockDim.x + threadIdx.x;
    const int b = blockIdx.y;
    const int o0 = 2 * t;
    if (o0 >= OUTLEN) return;

    const float* __restrict__ xb = x + (size_t)b * XLEN;
    const float* __restrict__ hb = h + (size_t)b * NB * LTOT;

    float acc0 = 0.f, acc1 = 0.f;

    const int p_lo = o0 - 23;             // lowest tap position (output o0)
    const int p_hi = o0 + 1;              // highest tap position (output o0+1)

    // Fast path: window fully inside xflat AND all taps in one frame.
    if (p_lo >= 1 && p_hi <= XLEN - 1) {
        const int f_lo = p_lo / TS;
        const int f_hi = p_hi / TS;       // <= 13 since p_hi <= 15343
        if (f_lo == f_hi) {
            // xw[k] = xflat[o0-24+k], k=0..25 ; 13 x float2, 8B-aligned:
            // byte offset = b*61376 + 4*(2t-24) = 8*(...)  (xw[0] is align pad)
            float xw[26];
            const float* base = xb + (o0 - 24);
            #pragma unroll
            for (int q = 0; q < 13; ++q) {
                float2 v = *(const float2*)(base + 2 * q);
                xw[2*q] = v.x; xw[2*q+1] = v.y;
            }
            float hw[LTOT];
            const float* hr = hb + f_hi * LTOT;   // 16B-aligned (96B rows)
            #pragma unroll
            for (int q = 0; q < 6; ++q) {
                float4 v = *(const float4*)(hr + 4 * q);
                hw[4*q]=v.x; hw[4*q+1]=v.y; hw[4*q+2]=v.z; hw[4*q+3]=v.w;
            }
            #pragma unroll
            for (int j = 0; j < LTOT; ++j) {      // all indices compile-time
                acc0 = fmaf(hw[j], xw[24 - j], acc0);
                acc1 = fmaf(hw[j], xw[25 - j], acc1);
            }
            float* ob = out + (size_t)b * OUTLEN + o0;
            ob[0] = acc0;
            ob[1] = acc1;                 // o0+1 <= XLEN-1 < OUTLEN-1: in range
            return;
        }
    }

    // Generic path: frame-straddling windows and array edges (~2.5% of waves).
    #pragma unroll
    for (int j = 0; j < LTOT; ++j) {
        const int p0 = o0 - j;
        if (p0 >= 0 && p0 < XLEN)
            acc0 = fmaf(hb[(p0 / TS) * LTOT + j], xb[p0], acc0);
        const int p1 = p0 + 1;
        if (p1 >= 0 && p1 < XLEN)
            acc1 = fmaf(hb[(p1 / TS) * LTOT + j], xb[p1], acc1);
    }
    float* ob = out + (size_t)b * OUTLEN + o0;
    ob[0] = acc0;
    if (o0 + 1 < OUTLEN) ob[1] = acc1;
}

extern "C" void kernel_launch(void* const* d_in, const int* in_sizes, int n_in,
                              void* d_out, int out_size, void* d_ws, size_t ws_size,
                              hipStream_t stream) {
    const float* x = (const float*)d_in[0];   // [B, NB, TS]  == [B, XLEN] flat
    const float* h = (const float*)d_in[1];   // [B, NB, LTOT]
    float* out = (float*)d_out;               // [B, OUTLEN]

    const int tiles = (OUTLEN + 1) / 2;       // 7684 threads per batch
    dim3 block(256, 1, 1);
    dim3 grid((tiles + 255) / 256, BATCH, 1); // (31, 128)
    atc_flat2_kernel<<<grid, block, 0, stream>>>(x, h, out);
}

// Round 4
// 11.912 us; speedup vs baseline: 2.6024x; 2.1297x over previous
//
#include <hip/hip_runtime.h>

#define BATCH  128
#define NB     14
#define TS     1096
#define LTOT   24
#define FRAME  (TS + LTOT - 1)            // 1119
#define OUTLEN ((NB - 1) * TS + FRAME)    // 15367
#define XLEN   (NB * TS)                  // 15344 (flat x per batch)
#define BS     256

// Flat formulation: out[b,o] = sum_{j=0..23} xflat[b,o-j] * h[b,(o-j)/TS, j]
// (taps outside [0, XLEN) contribute 0). Equivalent to per-frame conv +
// overlap_add because hop == per-frame x length == TS.
//
// Block = 256 consecutive outputs of one batch. Taps for the block span
// [o0-23, o0+255] (279 positions < TS) -> at most 2 h-rows per block.
__global__ __launch_bounds__(256)
void atc_lds_kernel(const float* __restrict__ x,
                    const float* __restrict__ h,
                    float* __restrict__ out) {
    const int b   = blockIdx.y;
    const int o0  = blockIdx.x * BS;
    const int tid = threadIdx.x;
    const int o   = o0 + tid;

    __shared__ __align__(16) float xs[BS + 32];   // xs[k] = xflat[b, o0-32+k]
    const float* __restrict__ xb = x + (size_t)b * XLEN;

    // ---- stage 288 floats (72 float4), zero-padding out-of-range ----
    if (tid < 72) {
        const int g = o0 - 32 + 4 * tid;          // 16B-aligned global offset
        const float* gp = xb + g;
        float4 v;
        if (g >= 0 && g + 4 <= XLEN) {
            v = *(const float4*)gp;
        } else {
            v.x = ((unsigned)(g + 0) < (unsigned)XLEN) ? gp[0] : 0.f;
            v.y = ((unsigned)(g + 1) < (unsigned)XLEN) ? gp[1] : 0.f;
            v.z = ((unsigned)(g + 2) < (unsigned)XLEN) ? gp[2] : 0.f;
            v.w = ((unsigned)(g + 3) < (unsigned)XLEN) ? gp[3] : 0.f;
        }
        *(float4*)(&xs[4 * tid]) = v;
    }
    __syncthreads();

    // ---- frame span of this block's valid taps (block-uniform) ----
    int pa = o0 - 23;      if (pa < 0) pa = 0;
    int pb = o0 + BS - 1;  if (pb > XLEN - 1) pb = XLEN - 1;
    const int fa = pa / TS;                       // magic-mul, compile-time TS
    const int fb = pb / TS;                       // fb == fa or fa+1

    const float* __restrict__ hA = h + ((size_t)b * NB + fa) * LTOT;
    float hwA[LTOT];
    #pragma unroll
    for (int q = 0; q < 6; ++q) {
        float4 v = *(const float4*)(hA + 4 * q);  // 96B rows -> 16B aligned
        hwA[4*q] = v.x; hwA[4*q+1] = v.y; hwA[4*q+2] = v.z; hwA[4*q+3] = v.w;
    }

    float acc = 0.f;
    if (fa == fb) {
        // fast path: single h-row, conflict-free LDS reads, all unrolled
        #pragma unroll
        for (int j = 0; j < LTOT; ++j)
            acc = fmaf(hwA[j], xs[32 + tid - j], acc);
    } else {
        // seam block: per-tap select between the two register h-rows
        const float* __restrict__ hB = h + ((size_t)b * NB + fb) * LTOT;
        float hwB[LTOT];
        #pragma unroll
        for (int q = 0; q < 6; ++q) {
            float4 v = *(const float4*)(hB + 4 * q);
            hwB[4*q] = v.x; hwB[4*q+1] = v.y; hwB[4*q+2] = v.z; hwB[4*q+3] = v.w;
        }
        const int sB = fb * TS;
        #pragma unroll
        for (int j = 0; j < LTOT; ++j) {
            const float hv = (o - j >= sB) ? hwB[j] : hwA[j];
            acc = fmaf(hv, xs[32 + tid - j], acc);
        }
    }

    if (o < OUTLEN)
        out[(size_t)b * OUTLEN + o] = acc;
}

extern "C" void kernel_launch(void* const* d_in, const int* in_sizes, int n_in,
                              void* d_out, int out_size, void* d_ws, size_t ws_size,
                              hipStream_t stream) {
    const float* x = (const float*)d_in[0];   // [B, NB, TS] == [B, XLEN] flat
    const float* h = (const float*)d_in[1];   // [B, NB, LTOT]
    float* out = (float*)d_out;               // [B, OUTLEN]

    dim3 block(BS, 1, 1);
    dim3 grid((OUTLEN + BS - 1) / BS, BATCH, 1);   // (61, 128) = 7808 blocks
    atc_lds_kernel<<<grid, block, 0, stream>>>(x, h, out);
}